// Round 1
// baseline (511.943 us; speedup 1.0000x reference)
//
#include <hip/hip_runtime.h>
#include <math.h>

// SwitchGate: T=16384 tokens, D=4096, E=64 experts, CAP_RATE=2.4.
// capacity = ceil(2.4*16384) = 39322 > T  =>  pruning NEVER triggers:
//   pruned_idx == top1_idx, n_valid == T.
// loss = (E / T^2) * sum_e count[e] * score_sum[e]
//
// Outputs concatenated in d_out (float32):
//   [0,T)    pruned_idx (as float)
//   [T,2T)   top1_score
//   [2T]     loss

#define T_TOK 16384
#define D_DIM 4096
#define E_EXP 64

// ---------------------------------------------------------------- zero ws
__global__ void zero_ws_kernel(float* __restrict__ wsf, int* __restrict__ wsc) {
    int t = threadIdx.x;
    if (t < 64) wsf[t] = 0.0f;
    else if (t < 128) wsc[t - 64] = 0;
}

// ---------------------------------------------------------------- main
// Block: 512 threads (8 waves). BM = 64 tokens, all 64 experts, BK = 32.
// Per thread: 2 tokens x 4 experts register tile.
__global__ __launch_bounds__(512) void gate_main_kernel(
    const float* __restrict__ inp,   // [T, D]
    const float* __restrict__ W,     // [E, D]
    const float* __restrict__ b,     // [E]
    float* __restrict__ out,         // [2T+1]
    float* __restrict__ g_sum,       // [64] global expert score sums
    int*   __restrict__ g_cnt)       // [64] global expert counts
{
    __shared__ float A_s[32][66];    // [k][token], pad 66 (even -> float2 ok)
    __shared__ float W_s[32][68];    // [k][expert], pad 68 (mult 4 -> float4 ok)
    __shared__ float lds_sum[E_EXP];
    __shared__ int   lds_cnt[E_EXP];

    const int tid = threadIdx.x;
    const int tx  = tid & 15;        // expert group: experts 4tx..4tx+3
    const int ty  = tid >> 4;        // 0..31: tokens 2ty, 2ty+1
    const int tok_base = blockIdx.x * 64;

    // staging mapping: 512 threads cover 64 rows x 32 k  (8 float4s per row)
    const int s_row = tid >> 3;          // 0..63  (token row / expert row)
    const int s_k4  = (tid & 7) * 4;     // 0,4,...,28

    if (tid < E_EXP) { lds_sum[tid] = 0.0f; lds_cnt[tid] = 0; }

    const float* a_ptr = inp + (size_t)(tok_base + s_row) * D_DIM + s_k4;
    const float* w_ptr = W   + (size_t)s_row * D_DIM + s_k4;

    float acc[2][4];
#pragma unroll
    for (int t = 0; t < 2; ++t)
#pragma unroll
        for (int j = 0; j < 4; ++j) acc[t][j] = 0.0f;

    for (int kc = 0; kc < D_DIM; kc += 32) {
        const float4 a4 = *(const float4*)(a_ptr + kc);
        const float4 w4 = *(const float4*)(w_ptr + kc);
        __syncthreads();   // previous chunk's compute done before overwrite
        A_s[s_k4 + 0][s_row] = a4.x;
        A_s[s_k4 + 1][s_row] = a4.y;
        A_s[s_k4 + 2][s_row] = a4.z;
        A_s[s_k4 + 3][s_row] = a4.w;
        W_s[s_k4 + 0][s_row] = w4.x;
        W_s[s_k4 + 1][s_row] = w4.y;
        W_s[s_k4 + 2][s_row] = w4.z;
        W_s[s_k4 + 3][s_row] = w4.w;
        __syncthreads();

#pragma unroll
        for (int k = 0; k < 32; ++k) {
            const float2 a = *(const float2*)&A_s[k][2 * ty];
            const float4 w = *(const float4*)&W_s[k][4 * tx];
            acc[0][0] += a.x * w.x;  acc[0][1] += a.x * w.y;
            acc[0][2] += a.x * w.z;  acc[0][3] += a.x * w.w;
            acc[1][0] += a.y * w.x;  acc[1][1] += a.y * w.y;
            acc[1][2] += a.y * w.z;  acc[1][3] += a.y * w.w;
        }
    }

    // ---- epilogue: add bias, per-token softmax/top1 across 16 lanes ----
    float bias[4];
#pragma unroll
    for (int j = 0; j < 4; ++j) bias[j] = b[4 * tx + j];

#pragma unroll
    for (int t = 0; t < 2; ++t) {
        const int token = tok_base + 2 * ty + t;
        float l[4];
#pragma unroll
        for (int j = 0; j < 4; ++j) l[j] = acc[t][j] + bias[j];

        // local max / argmax (ties -> lowest index, matching lax.top_k)
        float mv = l[0]; int mi = 4 * tx;
#pragma unroll
        for (int j = 1; j < 4; ++j)
            if (l[j] > mv) { mv = l[j]; mi = 4 * tx + j; }

        // reduce across the 16 lanes that share this token
#pragma unroll
        for (int off = 1; off < 16; off <<= 1) {
            float ov = __shfl_xor(mv, off, 16);
            int   oi = __shfl_xor(mi, off, 16);
            if (ov > mv || (ov == mv && oi < mi)) { mv = ov; mi = oi; }
        }

        float s = 0.0f;
        float ex[4];
#pragma unroll
        for (int j = 0; j < 4; ++j) { ex[j] = __expf(l[j] - mv); s += ex[j]; }
#pragma unroll
        for (int off = 1; off < 16; off <<= 1) s += __shfl_xor(s, off, 16);
        const float inv = 1.0f / s;   // == top1 score (exp(mv-mv)/s)

        // per-expert score sums (block-local)
#pragma unroll
        for (int j = 0; j < 4; ++j) atomicAdd(&lds_sum[4 * tx + j], ex[j] * inv);

        if (tx == 0) {
            out[token]          = (float)mi;   // pruned_idx (never capacity-pruned)
            out[T_TOK + token]  = inv;         // top1_score
            atomicAdd(&lds_cnt[mi], 1);
        }
    }

    __syncthreads();
    if (tid < E_EXP) {
        atomicAdd(&g_sum[tid], lds_sum[tid]);
        atomicAdd(&g_cnt[tid], lds_cnt[tid]);
    }
}

// ---------------------------------------------------------------- loss
__global__ void gate_loss_kernel(const float* __restrict__ g_sum,
                                 const int* __restrict__ g_cnt,
                                 float* __restrict__ out) {
    const int e = threadIdx.x;   // 64 threads = 1 wave
    float v = g_sum[e] * (float)g_cnt[e];
#pragma unroll
    for (int off = 32; off > 0; off >>= 1) v += __shfl_xor(v, off, 64);
    if (e == 0)
        out[2 * T_TOK] = v * (float)E_EXP / ((float)T_TOK * (float)T_TOK);
}

// ---------------------------------------------------------------- launch
extern "C" void kernel_launch(void* const* d_in, const int* in_sizes, int n_in,
                              void* d_out, int out_size, void* d_ws, size_t ws_size,
                              hipStream_t stream) {
    const float* inp = (const float*)d_in[0];
    const float* W   = (const float*)d_in[1];
    const float* b   = (const float*)d_in[2];
    float* out = (float*)d_out;

    float* g_sum = (float*)d_ws;           // 64 floats
    int*   g_cnt = (int*)(g_sum + 64);     // 64 ints

    zero_ws_kernel<<<1, 128, 0, stream>>>(g_sum, g_cnt);
    gate_main_kernel<<<T_TOK / 64, 512, 0, stream>>>(inp, W, b, out, g_sum, g_cnt);
    gate_loss_kernel<<<1, 64, 0, stream>>>(g_sum, g_cnt, out);
}